// Round 5
// baseline (270.004 us; speedup 1.0000x reference)
//
#include <hip/hip_runtime.h>
#include <hip/hip_bf16.h>

#define S_LEN 2048
#define NB    32      // batch
#define EMB   1024
#define ATT   512
#define HID   1024

typedef float f32x4  __attribute__((ext_vector_type(4)));
typedef short s16x4  __attribute__((ext_vector_type(4)));
typedef short s16x8  __attribute__((ext_vector_type(8)));

static __device__ __forceinline__ short f2bf(float f) {
    return __builtin_bit_cast(short, __float2bfloat16(f));
}
static __device__ __forceinline__ float tanh_fast(float x) {
    float e = __expf(2.0f * x);
    return 1.0f - 2.0f / (e + 1.0f);
}

#define GLOAD_LDS16(gp, lp)                                                   \
    __builtin_amdgcn_global_load_lds(                                         \
        (const __attribute__((address_space(1))) void*)(gp),                  \
        (__attribute__((address_space(3))) void*)(uintptr_t)(lp), 16, 0, 0)

// ---------------- K1: hid_comb[b][a] = hid[b,:]@W_hid[:,a] + b_hid[a] + b_emb[a]
__global__ void k_hidcomb(const float* __restrict__ hid,
                          const float* __restrict__ W_hid,
                          const float* __restrict__ b_hid,
                          const float* __restrict__ b_emb,
                          float* __restrict__ hid_comb) {
    int gid = blockIdx.x * 256 + threadIdx.x;   // 32*512 = 16384
    int b = gid >> 9, a = gid & 511;
    const float* hr = hid + b * HID;
    float acc = 0.f;
#pragma unroll 4
    for (int k = 0; k < HID; ++k) acc += hr[k] * W_hid[k * ATT + a];
    hid_comb[gid] = acc + b_hid[a] + b_emb[a];
}

// ---------------- K2: W_T[a][k] = bf16(W_emb[k][a])
__global__ void k_wt(const float* __restrict__ W, unsigned short* __restrict__ WT) {
    __shared__ float tile[32][33];
    int k0 = blockIdx.x * 32, a0 = blockIdx.y * 32;
    int tx = threadIdx.x, ty = threadIdx.y;     // 32 x 8
#pragma unroll
    for (int i = 0; i < 32; i += 8)
        tile[ty + i][tx] = W[(size_t)(k0 + ty + i) * ATT + a0 + tx];
    __syncthreads();
#pragma unroll
    for (int i = 0; i < 32; i += 8)
        WT[(size_t)(a0 + ty + i) * HID + k0 + tx] =
            (unsigned short)f2bf(tile[tx][ty + i]);
}

// ---------------- K3: 128x128 GEMM; 4 waves x (64x64); A reg-staged f32->bf16
// swizzled ds_write (2 bufs); B via global_load_lds (3 bufs); loads issued 2
// tiles ahead, per-body s_waitcnt vmcnt(6) (counted, never drained to 0).
// Fused tanh + dot(att_v) epilogue -> 8 score slices (no atomics).
__global__ __launch_bounds__(256, 3) void k_gemm_scores(
        const float* __restrict__ emb,
        const unsigned short* __restrict__ WT,
        const float* __restrict__ hid_comb,
        const float* __restrict__ att_v,
        float* __restrict__ part) {           // part[slice][b][s], slice=0..7
    __shared__ __align__(16) unsigned short lA[2 * 128 * 32];  // bf16, 8KB/buf
    __shared__ __align__(16) unsigned short lB[3 * 128 * 32];  // bf16, 8KB/buf

    // XCD swizzle: 2048 wgs, 8 XCDs; all 4 n-tiles of an m-panel on one XCD.
    int bid = blockIdx.x;
    int t2 = (bid & 7) * 256 + (bid >> 3);
    int mt = t2 >> 2, nt = t2 & 3;
    int m0 = mt * 128, n0 = nt * 128;

    int tid  = threadIdx.x;
    int lane = tid & 63, wave = tid >> 6;
    int wr = wave >> 1, wc = wave & 1;
    int row_l = lane & 15;        // fragment row (A) / col (B,D)
    int kg    = lane >> 4;        // k-group: k = kg*8 + i

    // ---- A staging map: 1024 16B-f32 chunks; 4/thread -> 8B bf16 in LDS
    const float* aSrc[4];
    int aWoff[4];
#pragma unroll
    for (int j = 0; j < 4; ++j) {
        int c = j * 256 + tid;
        int r = c >> 3, pos = c & 7;
        aSrc[j]  = emb + (size_t)(m0 + r) * EMB + pos * 4;
        aWoff[j] = r * 64 + (((pos >> 1) ^ ((r >> 1) & 3)) * 16) + (pos & 1) * 8;
    }
    // ---- B staging map (pre-swizzled source, linear LDS dest)
    const unsigned short* bSrc[2];
    int bDst[2];
#pragma unroll
    for (int j = 0; j < 2; ++j) {
        int c = j * 256 + tid;
        int r = c >> 2, pos = c & 3;
        bSrc[j] = WT + (size_t)(n0 + r) * HID + (pos ^ ((r >> 1) & 3)) * 8;
        bDst[j] = c * 16;
    }
    // ---- fragment read byte-offsets (swizzled)
    int aoff[4], boff[4];
#pragma unroll
    for (int mf = 0; mf < 4; ++mf) {
        int row = wr * 64 + mf * 16 + row_l;
        aoff[mf] = row * 64 + ((kg ^ ((row >> 1) & 3)) * 16);
    }
#pragma unroll
    for (int nf = 0; nf < 4; ++nf) {
        int row = wc * 64 + nf * 16 + row_l;
        boff[nf] = row * 64 + ((kg ^ ((row >> 1) & 3)) * 16);
    }

    f32x4 acc[4][4] = {};
    f32x4 s0[4], s1[4];           // two A-reg sets (static indexing only)
    char* lAB = (char*)lA;
    char* lBB = (char*)lB;

    // ---- prologue: B(0),B(1) DMA; A(0)->s0, A(1)->s1; write A(0); A(2)->s0
#pragma unroll
    for (int j = 0; j < 2; ++j) GLOAD_LDS16(bSrc[j],      lBB +        bDst[j]);
#pragma unroll
    for (int j = 0; j < 2; ++j) GLOAD_LDS16(bSrc[j] + 32, lBB + 8192 + bDst[j]);
#pragma unroll
    for (int j = 0; j < 4; ++j) s0[j] = *(const f32x4*)(aSrc[j]);
#pragma unroll
    for (int j = 0; j < 4; ++j) s1[j] = *(const f32x4*)(aSrc[j] + 32);
#pragma unroll
    for (int j = 0; j < 4; ++j) {
        s16x4 w;
        w[0] = f2bf(s0[j][0]); w[1] = f2bf(s0[j][1]);
        w[2] = f2bf(s0[j][2]); w[3] = f2bf(s0[j][3]);
        *(s16x4*)(lAB + aWoff[j]) = w;
    }
#pragma unroll
    for (int j = 0; j < 4; ++j) s0[j] = *(const f32x4*)(aSrc[j] + 64);
    asm volatile("s_waitcnt lgkmcnt(0)\n\ts_barrier" ::: "memory");

    int kk = 0;        // current tile k-offset (elements)
    int b0 = 0;        // B-buf of current tile
    int b2 = 2;        // B-buf of tile cur+2 (DMA target)

#define GBODY(SREG, ABR, ABW)                                                  \
    {                                                                          \
        _Pragma("unroll")                                                      \
        for (int j = 0; j < 4; ++j) {              /* ds_write A(cur+1) */     \
            s16x4 w;                                                           \
            w[0] = f2bf(SREG[j][0]); w[1] = f2bf(SREG[j][1]);                  \
            w[2] = f2bf(SREG[j][2]); w[3] = f2bf(SREG[j][3]);                  \
            *(s16x4*)(lAB + (ABW) * 8192 + aWoff[j]) = w;                      \
        }                                                                      \
        int kb = (kk + 64) & 1023;                 /* B(cur+2) DMA */          \
        _Pragma("unroll")                                                      \
        for (int j = 0; j < 2; ++j)                                            \
            GLOAD_LDS16(bSrc[j] + kb, lBB + b2 * 8192 + bDst[j]);              \
        int ka = (kk + 96) & 1023;                 /* A(cur+3) -> regs */      \
        _Pragma("unroll")                                                      \
        for (int j = 0; j < 4; ++j) SREG[j] = *(const f32x4*)(aSrc[j] + ka);   \
        const char* pa = lAB + (ABR) * 8192;                                   \
        const char* pb = lBB + b0 * 8192;                                      \
        s16x8 af[4], bf[4];                                                    \
        _Pragma("unroll")                                                      \
        for (int mf = 0; mf < 4; ++mf)                                         \
            af[mf] = *(const s16x8*)(pa + aoff[mf]);                           \
        _Pragma("unroll")                                                      \
        for (int nf = 0; nf < 4; ++nf)                                         \
            bf[nf] = *(const s16x8*)(pb + boff[nf]);                           \
        _Pragma("unroll")                                                      \
        for (int mf = 0; mf < 4; ++mf)                                         \
            _Pragma("unroll")                                                  \
            for (int nf = 0; nf < 4; ++nf)                                     \
                acc[mf][nf] = __builtin_amdgcn_mfma_f32_16x16x32_bf16(         \
                    af[mf], bf[nf], acc[mf][nf], 0, 0, 0);                     \
        asm volatile("s_waitcnt vmcnt(6) lgkmcnt(0)\n\ts_barrier" ::: "memory"); \
        kk += 32;                                                              \
        b0 = (b0 == 2) ? 0 : b0 + 1;                                           \
        b2 = (b2 == 2) ? 0 : b2 + 1;                                           \
    }

    for (int it = 0; it < 16; ++it) {
        GBODY(s1, 0, 1)     // even tile: read Abuf0, write A(cur+1)->Abuf1
        GBODY(s0, 1, 0)     // odd tile:  read Abuf1, write A(cur+1)->Abuf0
    }
#undef GBODY

    // ---- epilogue: score partial for this 64-col wave slice
    float vv[4];
#pragma unroll
    for (int nf = 0; nf < 4; ++nf)
        vv[nf] = att_v[n0 + wc * 64 + nf * 16 + row_l];

    int slice = nt * 2 + wc;
#pragma unroll
    for (int mf = 0; mf < 4; ++mf) {
#pragma unroll
        for (int j = 0; j < 4; ++j) {
            int m = m0 + wr * 64 + mf * 16 + kg * 4 + j;   // D row
            int b = m & 31;
            int s = m >> 5;
            const float* ad = hid_comb + b * ATT + n0 + wc * 64;
            float sum = 0.f;
#pragma unroll
            for (int nf = 0; nf < 4; ++nf) {
                float x = acc[mf][nf][j] + ad[nf * 16 + row_l];
                sum += tanh_fast(x) * vv[nf];
            }
#pragma unroll
            for (int d = 1; d < 16; d <<= 1)
                sum += __shfl_xor(sum, d, 64);
            if (row_l == 0)
                part[slice * (NB * S_LEN) + b * S_LEN + s] = sum;
        }
    }
}

// ---------------- K4: softmax over S per batch row (sums the 8 n-slices)
__global__ void k_softmax(const float* __restrict__ part,
                          float* __restrict__ weights) {
    int b = blockIdx.x, tid = threadIdx.x;  // 256 threads
    float v[8];
    float mx = -1e30f;
#pragma unroll
    for (int i = 0; i < 8; ++i) {
        int s = i * 256 + tid;
        float sc = 0.f;
#pragma unroll
        for (int p = 0; p < 8; ++p)
            sc += part[p * (NB * S_LEN) + b * S_LEN + s];
        v[i] = sc;
        mx = fmaxf(mx, sc);
    }
#pragma unroll
    for (int d = 1; d < 64; d <<= 1) mx = fmaxf(mx, __shfl_xor(mx, d, 64));
    __shared__ float sm[4], ss[4];
    if ((tid & 63) == 0) sm[tid >> 6] = mx;
    __syncthreads();
    mx = fmaxf(fmaxf(sm[0], sm[1]), fmaxf(sm[2], sm[3]));
    float sum = 0.f;
#pragma unroll
    for (int i = 0; i < 8; ++i) {
        v[i] = __expf(v[i] - mx);
        sum += v[i];
    }
#pragma unroll
    for (int d = 1; d < 64; d <<= 1) sum += __shfl_xor(sum, d, 64);
    if ((tid & 63) == 0) ss[tid >> 6] = sum;
    __syncthreads();
    sum = ss[0] + ss[1] + ss[2] + ss[3];
    float inv = 1.0f / sum;
#pragma unroll
    for (int i = 0; i < 8; ++i)
        weights[b * S_LEN + i * 256 + tid] = v[i] * inv;
}

// ---------------- K5: context partials over s-chunks (f32 emb)
__global__ void k_ctx1(const float* __restrict__ emb,
                       const float* __restrict__ weights,
                       float* __restrict__ cpart) {
    int sc = blockIdx.x, b = blockIdx.y, t = threadIdx.x;
    const f32x4* ep = (const f32x4*)emb;
    f32x4 acc = {0.f, 0.f, 0.f, 0.f};
    int s0 = sc * 128;
    for (int i = 0; i < 128; i += 4) {
#pragma unroll
        for (int u = 0; u < 4; ++u) {
            int s = s0 + i + u;
            float w = weights[b * S_LEN + s];
            f32x4 x = ep[(size_t)(s * NB + b) * 256 + t];
            acc += w * x;
        }
    }
    ((f32x4*)cpart)[(size_t)(sc * NB + b) * 256 + t] = acc;
}

// ---------------- K6: reduce partials -> context (d_out front)
__global__ void k_ctx2(const float* __restrict__ cpart, float* __restrict__ ctx) {
    int i = blockIdx.x * 256 + threadIdx.x;   // 32*1024
    float s = 0.f;
#pragma unroll
    for (int sc = 0; sc < 16; ++sc) s += cpart[sc * (NB * EMB) + i];
    ctx[i] = s;
}

extern "C" void kernel_launch(void* const* d_in, const int* in_sizes, int n_in,
                              void* d_out, int out_size, void* d_ws, size_t ws_size,
                              hipStream_t stream) {
    const float* hid   = (const float*)d_in[0];
    const float* emb   = (const float*)d_in[1];
    const float* W_hid = (const float*)d_in[2];
    const float* b_hid = (const float*)d_in[3];
    const float* W_emb = (const float*)d_in[4];
    const float* b_emb = (const float*)d_in[5];
    const float* att_v = (const float*)d_in[6];

    float* out     = (float*)d_out;
    float* ctx     = out;                // 32*1024
    float* weights = out + NB * EMB;     // 32*2048

    char* ws = (char*)d_ws;
    float*          part     = (float*)(ws);                    // 2 MiB (8 slices)
    float*          hid_comb = (float*)(ws + 2097152);          // 64 KiB
    unsigned short* WT       = (unsigned short*)(ws + 2162688); // 1 MiB
    float*          cpart    = (float*)(ws + 3211264);          // 2 MiB

    k_hidcomb<<<64, 256, 0, stream>>>(hid, W_hid, b_hid, b_emb, hid_comb);
    k_wt<<<dim3(32, 16), dim3(32, 8), 0, stream>>>(W_emb, WT);
    k_gemm_scores<<<2048, 256, 0, stream>>>(emb, WT, hid_comb, att_v, part);
    k_softmax<<<NB, 256, 0, stream>>>(part, weights);
    k_ctx1<<<dim3(16, NB), 256, 0, stream>>>(emb, weights, cpart);
    k_ctx2<<<128, 256, 0, stream>>>(cpart, ctx);
}